// Round 15
// baseline (535.307 us; speedup 1.0000x reference)
//
#include <hip/hip_runtime.h>
#include <math.h>

#define NSEQ 430
#define SEQL 25
#define EMB  20
#define SVS  10
#define NH   5
#define FFND 10
#define NL   4
#define BB   32           // batch used as sequence axis (S)
#define NT   1024         // 16 waves, 32 halfwaves (25 real, 7 clamped dummies)
#define NCOLS 32          // pool columns incl. private dummy slots

__device__ __forceinline__ void cp_lds(float* dst, const float* src, int n, int tid) {
    for (int k = tid; k < n; k += NT) dst[k] = src[k];
}

// dot of 20 per-lane values with a WAVE-UNIFORM global weight row (s_load path)
__device__ __forceinline__ float dot20g(const float* x, const float* __restrict__ w, float acc) {
#pragma unroll
    for (int j = 0; j < 20; ++j) acc = fmaf(x[j], w[j], acc);
    return acc;
}

template<int N>
__device__ __forceinline__ void ln_vec(float* v, const float* __restrict__ g,
                                       const float* __restrict__ b) {
    float m = 0.f;
#pragma unroll
    for (int e = 0; e < N; e++) m += v[e];
    m *= (1.0f / N);
    float var = 0.f;
#pragma unroll
    for (int e = 0; e < N; e++) { float d = v[e] - m; var = fmaf(d, d, var); }
    var *= (1.0f / N);
    float rs = rsqrtf(var + 1e-5f);
#pragma unroll
    for (int e = 0; e < N; e++) v[e] = (v[e] - m) * rs * g[e] + b[e];
}

// 2 blocks/CU: min 8 waves/EU (VGPR<=64), 430 blocks pack as 215 CUs x 2, no tail
__global__ void __launch_bounds__(NT, 8)
enc_kernel(const float* __restrict__ X,
           const float* __restrict__ Wqkv, const float* __restrict__ bqkv,
           const float* __restrict__ Wo,   const float* __restrict__ bo,
           const float* __restrict__ W1,   const float* __restrict__ b1,
           const float* __restrict__ W2,   const float* __restrict__ b2,
           const float* __restrict__ g1,   const float* __restrict__ be1,
           const float* __restrict__ g2,   const float* __restrict__ be2,
           const float* __restrict__ linW, const float* __restrict__ linb,
           const float* __restrict__ sWqkv,const float* __restrict__ sbqkv,
           const float* __restrict__ sWo,  const float* __restrict__ sbo,
           const float* __restrict__ sW1,  const float* __restrict__ sb1,
           const float* __restrict__ sW2,  const float* __restrict__ sb2,
           const float* __restrict__ sg1,  const float* __restrict__ sbe1,
           const float* __restrict__ sg2,  const float* __restrict__ sbe2,
           float* __restrict__ sec)
{
    // per-halfwave K/V staging (layers) then lin partials; each halfwave owns its slice
    __shared__ __align__(16) float pool[NCOLS * BB * 12];   // 49152 B
    __shared__ float stx[BB][SVS];
    __shared__ float stqkv[BB][3*SVS];
    __shared__ float sttmp[BB][SVS];
    // small LDS staging for the st-encoder only
    __shared__ float pqW[300], pqB[30], poW[100], poB[10];
    __shared__ float p1W[100], p1B[10], p2W[100], p2B[10];
    __shared__ float pg1[10], pbe1[10], pg2[10], pbe2[10];

    const int i   = blockIdx.x;
    const int tid = threadIdx.x;
    const int hw  = tid >> 5;                    // halfwave id 0..31
    const int s   = tid & 31;                    // s index (the B axis)
    const int ncol = (hw < SEQL) ? hw : (SEQL - 1);   // clamp: uniform control flow

    // ---- token row in REGISTERS across all layers
    float x[20];
    {
        const float4* xr4 = (const float4*)(X + (((size_t)s * NSEQ + i) * SEQL + ncol) * EMB);
#pragma unroll
        for (int j = 0; j < 5; ++j) {
            float4 t4 = xr4[j];
            x[4*j+0] = t4.x; x[4*j+1] = t4.y; x[4*j+2] = t4.z; x[4*j+3] = t4.w;
        }
#pragma unroll
        for (int j = 0; j < 10; ++j) {
            float div = expf(-0.9210340371976184f * (float)j); // 10000^(-j/10)
            float ang = (float)s * div;
            x[2*j]   += sinf(ang);
            x[2*j+1] += cosf(ang);
        }
    }

    float4* my4 = (float4*)&pool[(hw * BB + s) * 12];
    const float4* kvr4 = (const float4*)&pool[hw * BB * 12];

    // ---------------- per-index transformer: 4 layers, ZERO barriers ----------
#pragma unroll 1
    for (int l = 0; l < NL; ++l) {
        const size_t po = (size_t)i * NL + l;
        const float* Wq  = Wqkv + po * 1200;
        const float* bq  = bqkv + po * 60;
        const float* Wog = Wo   + po * 400;
        const float* bog = bo   + po * 20;
        const float* W1g = W1   + po * 200;
        const float* b1g = b1   + po * 10;
        const float* W2g = W2   + po * 200;
        const float* b2g = b2   + po * 20;
        const float* g1g = g1   + po * 20;
        const float* e1g = be1  + po * 20;
        const float* g2g = g2   + po * 20;
        const float* e2g = be2  + po * 20;

        float out[20];
#pragma unroll
        for (int h = 0; h < NH; ++h) {
            float q[4], k[4], v[4];
#pragma unroll
            for (int d = 0; d < 4; ++d) {
                const int f = h * 4 + d;
                q[d] = dot20g(x, Wq + f * 20,        bq[f]) * 0.72134752044f; // 0.5*log2e
                k[d] = dot20g(x, Wq + (20 + f) * 20, bq[20 + f]);
                v[d] = dot20g(x, Wq + (40 + f) * 20, bq[40 + f]);
            }
            // stage k,v (same-wave in-order LDS: no barrier needed)
            my4[0] = make_float4(k[0], k[1], k[2], k[3]);
            my4[1] = make_float4(v[0], v[1], v[2], v[3]);
            float den = 0.f, o0 = 0.f, o1 = 0.f, o2 = 0.f, o3 = 0.f;
#pragma unroll 4
            for (int t = 0; t < BB; ++t) {
                float4 kt = kvr4[t * 3 + 0];
                float4 vt = kvr4[t * 3 + 1];
                float sc = fmaf(q[0], kt.x, fmaf(q[1], kt.y, fmaf(q[2], kt.z, q[3] * kt.w)));
                float p = exp2f(sc);      // base change; ratios identical
                den += p;
                o0 = fmaf(p, vt.x, o0);
                o1 = fmaf(p, vt.y, o1);
                o2 = fmaf(p, vt.z, o2);
                o3 = fmaf(p, vt.w, o3);
            }
            float inv = 1.0f / den;
            out[4*h+0] = o0 * inv;
            out[4*h+1] = o1 * inv;
            out[4*h+2] = o2 * inv;
            out[4*h+3] = o3 * inv;
        }
        // out-proj + residual + LN1
        float cr[20];
#pragma unroll
        for (int e = 0; e < 20; ++e)
            cr[e] = x[e] + dot20g(out, Wog + e * 20, bog[e]);
        ln_vec<20>(cr, g1g, e1g);
        // FFN + residual + LN2
        float hb[FFND];
#pragma unroll
        for (int j = 0; j < FFND; ++j)
            hb[j] = fmaxf(dot20g(cr, W1g + j * 20, b1g[j]), 0.f);
#pragma unroll
        for (int e = 0; e < 20; ++e) {
            const float* w2 = W2g + e * FFND;
            float acc = b2g[e];
#pragma unroll
            for (int m = 0; m < FFND; ++m) acc = fmaf(hb[m], w2[m], acc);
            x[e] = cr[e] + acc;
        }
        ln_vec<20>(x, g2g, e2g);
    }

    // ---------------- per-index Linear(500 -> 10): partials into pool ---------
    if (hw < SEQL) {
        const float* lwb = linW + (size_t)i * SVS * (SEQL * EMB);
        float* slot = &pool[(hw * BB + s) * 12];
#pragma unroll
        for (int o = 0; o < SVS; ++o) {
            const float* wr = lwb + o * (SEQL * EMB) + ncol * EMB;
            float acc = 0.f;
#pragma unroll
            for (int j = 0; j < 20; ++j) acc = fmaf(x[j], wr[j], acc);
            slot[o] = acc;
        }
    }
    __syncthreads();
    if (tid < BB * SVS) {
        const int b = tid / SVS, o = tid % SVS;
        float acc = linb[i * SVS + o];
#pragma unroll
        for (int n = 0; n < SEQL; ++n) acc += pool[(n * BB + b) * 12 + o];
        stx[b][o] = acc;
    }

    // ---------------- st transformer, column i only: [32, 10] ----------------
#pragma unroll 1
    for (int l = 0; l < NL; ++l) {
        __syncthreads();          // protect staging overwrite & stx writes
        cp_lds(pqW, sWqkv + l * 300, 300, tid);
        cp_lds(pqB, sbqkv + l * 30,  30,  tid);
        cp_lds(poW, sWo   + l * 100, 100, tid);
        cp_lds(poB, sbo   + l * 10,  10,  tid);
        cp_lds(p1W, sW1   + l * 100, 100, tid);
        cp_lds(p1B, sb1   + l * 10,  10,  tid);
        cp_lds(p2W, sW2   + l * 100, 100, tid);
        cp_lds(p2B, sb2   + l * 10,  10,  tid);
        cp_lds(pg1, sg1   + l * 10,  10,  tid);
        cp_lds(pbe1, sbe1 + l * 10,  10,  tid);
        cp_lds(pg2, sg2   + l * 10,  10,  tid);
        cp_lds(pbe2, sbe2 + l * 10,  10,  tid);
        __syncthreads();

        if (tid < BB * 3 * SVS) {  // qkv: 960 dots of length 10 (960 < 1024 OK)
            int s2 = tid / (3 * SVS), f = tid % (3 * SVS);
            float acc = pqB[f];
#pragma unroll
            for (int e = 0; e < SVS; e++) acc = fmaf(stx[s2][e], pqW[f * SVS + e], acc);
            stqkv[s2][f] = acc;
        }
        __syncthreads();

        if (tid < BB * NH) {       // attention per (s, h), D=2; single pass
            int s2 = tid / NH, h = tid % NH;
            float q0 = stqkv[s2][h * 2], q1 = stqkv[s2][h * 2 + 1];
            float den = 0.f, o0 = 0.f, o1 = 0.f;
#pragma unroll
            for (int t = 0; t < BB; t++) {
                float d0 = q0 * stqkv[t][SVS + h * 2] + q1 * stqkv[t][SVS + h * 2 + 1];
                float p = __expf(0.70710678118f * d0);
                den += p;
                o0 = fmaf(p, stqkv[t][2 * SVS + h * 2],     o0);
                o1 = fmaf(p, stqkv[t][2 * SVS + h * 2 + 1], o1);
            }
            float inv = 1.0f / den;
            sttmp[s2][h * 2]     = o0 * inv;
            sttmp[s2][h * 2 + 1] = o1 * inv;
        }
        __syncthreads();

        if (tid < BB) {            // proj + LN1 + FFN + LN2, token-local
            int s2 = tid;
            float cr[SVS];
#pragma unroll
            for (int e = 0; e < SVS; e++) {
                float acc = poB[e];
#pragma unroll
                for (int f = 0; f < SVS; f++) acc = fmaf(sttmp[s2][f], poW[e * SVS + f], acc);
                cr[e] = stx[s2][e] + acc;
            }
            ln_vec<SVS>(cr, pg1, pbe1);
            float hb[FFND];
#pragma unroll
            for (int j = 0; j < FFND; j++) {
                float acc = p1B[j];
#pragma unroll
                for (int e = 0; e < SVS; e++) acc = fmaf(cr[e], p1W[j * SVS + e], acc);
                hb[j] = fmaxf(acc, 0.f);
            }
            float fr[SVS];
#pragma unroll
            for (int e = 0; e < SVS; e++) {
                float acc = p2B[e];
#pragma unroll
                for (int j = 0; j < FFND; j++) acc = fmaf(hb[j], p2W[e * FFND + j], acc);
                fr[e] = cr[e] + acc;
            }
            ln_vec<SVS>(fr, pg2, pbe2);
#pragma unroll
            for (int e = 0; e < SVS; e++) stx[s2][e] = fr[e];
        }
        __syncthreads();
    }

    // write sec[b][i][o] (fp32 workspace)
    if (tid < BB * SVS) {
        int b = tid / SVS, o = tid % SVS;
        sec[(size_t)b * (NSEQ * SVS) + (size_t)i * SVS + o] = stx[b][o];
    }
}

__global__ __launch_bounds__(256, 1)
void head_kernel(const float* __restrict__ sec,
                 const float* __restrict__ plW, const float* __restrict__ plb,
                 const float* __restrict__ llW, const float* __restrict__ llb,
                 float* __restrict__ out)
{
    const int b = blockIdx.x, tid = threadIdx.x;
    const float* fb = sec + (size_t)b * (NSEQ * SVS);
    float acc[8];
#pragma unroll
    for (int p = 0; p < 8; p++) acc[p] = 0.f;
    for (int f = tid; f < NSEQ * SVS; f += 256) {
        float xv = fb[f];
#pragma unroll
        for (int p = 0; p < 8; p++)
            acc[p] = fmaf(xv, plW[p * (NSEQ * SVS) + f], acc[p]);
    }
#pragma unroll
    for (int p = 0; p < 8; p++) {
#pragma unroll
        for (int off = 32; off > 0; off >>= 1)
            acc[p] += __shfl_down(acc[p], off, 64);
    }
    __shared__ float red[4][8];
    const int wv = tid >> 6, ln = tid & 63;
    if (ln == 0) {
#pragma unroll
        for (int p = 0; p < 8; p++) red[wv][p] = acc[p];
    }
    __syncthreads();
    if (tid == 0) {
        float s8[8];
#pragma unroll
        for (int p = 0; p < 8; p++)
            s8[p] = red[0][p] + red[1][p] + red[2][p] + red[3][p] + plb[p];
#pragma unroll
        for (int qq = 0; qq < 2; qq++) {
            float o = llb[qq];
#pragma unroll
            for (int p = 0; p < 8; p++) o = fmaf(s8[p], llW[qq * 8 + p], o);
            out[b * 2 + qq] = o;
        }
    }
}

extern "C" void kernel_launch(void* const* d_in, const int* in_sizes, int n_in,
                              void* d_out, int out_size, void* d_ws, size_t ws_size,
                              hipStream_t stream)
{
    const float* X     = (const float*)d_in[0];
    const float* Wqkv  = (const float*)d_in[1];
    const float* bqkv  = (const float*)d_in[2];
    const float* Wo    = (const float*)d_in[3];
    const float* bo    = (const float*)d_in[4];
    const float* W1    = (const float*)d_in[5];
    const float* b1    = (const float*)d_in[6];
    const float* W2    = (const float*)d_in[7];
    const float* b2    = (const float*)d_in[8];
    const float* g1    = (const float*)d_in[9];
    const float* be1   = (const float*)d_in[10];
    const float* g2    = (const float*)d_in[11];
    const float* be2   = (const float*)d_in[12];
    const float* linW  = (const float*)d_in[13];
    const float* linb  = (const float*)d_in[14];
    const float* sWqkv = (const float*)d_in[15];
    const float* sbqkv = (const float*)d_in[16];
    const float* sWo   = (const float*)d_in[17];
    const float* sbo   = (const float*)d_in[18];
    const float* sW1   = (const float*)d_in[19];
    const float* sb1   = (const float*)d_in[20];
    const float* sW2   = (const float*)d_in[21];
    const float* sb2   = (const float*)d_in[22];
    const float* sg1   = (const float*)d_in[23];
    const float* sbe1  = (const float*)d_in[24];
    const float* sg2   = (const float*)d_in[25];
    const float* sbe2  = (const float*)d_in[26];
    const float* plW   = (const float*)d_in[27];
    const float* plb   = (const float*)d_in[28];
    const float* llW   = (const float*)d_in[29];
    const float* llb   = (const float*)d_in[30];

    float* sec = (float*)d_ws;   // 32*430*10 fp32 = 550,400 B

    enc_kernel<<<NSEQ, NT, 0, stream>>>(X, Wqkv, bqkv, Wo, bo, W1, b1, W2, b2,
                                        g1, be1, g2, be2, linW, linb,
                                        sWqkv, sbqkv, sWo, sbo, sW1, sb1, sW2, sb2,
                                        sg1, sbe1, sg2, sbe2, sec);
    head_kernel<<<BB, 256, 0, stream>>>(sec, plW, plb, llW, llb, (float*)d_out);
}

// Round 16
// 408.049 us; speedup vs baseline: 1.3119x; 1.3119x over previous
//
#include <hip/hip_runtime.h>
#include <math.h>

#define NSEQ 430
#define SEQL 25
#define EMB  20
#define SVS  10
#define NH   5
#define FFND 10
#define NL   4
#define BB   32           // batch used as sequence axis (S)
#define NTA  256          // kernel A: 4 waves, 8 halfwaves = 8 columns
#define BPI  4            // blocks per index i (8+8+8+1 columns)
#define NTB  320          // kernel B threads

// packed per-layer LDS weight layout (floats; all offsets multiple of 4 -> 16B aligned)
#define LSTR  2192
#define OWQKV 0
#define OWO   1200
#define OW1   1600
#define OW2   1800
#define OBQKV 2000
#define OBO   2060
#define OB1   2080
#define OB2   2092
#define OG1   2112
#define OBE1  2132
#define OG2   2152
#define OBE2  2172

__device__ __forceinline__ void cp_lds(float* dst, const float* src, int n, int tid, int nt) {
    for (int k = tid; k < n; k += nt) dst[k] = src[k];
}

// dot of 20 per-lane values with an LDS row (5x ds_read_b128 broadcast)
__device__ __forceinline__ float dot20L(const float* x, const float4* w4, float acc) {
#pragma unroll
    for (int j = 0; j < 5; ++j) {
        float4 wv = w4[j];
        acc = fmaf(x[4*j+0], wv.x, acc);
        acc = fmaf(x[4*j+1], wv.y, acc);
        acc = fmaf(x[4*j+2], wv.z, acc);
        acc = fmaf(x[4*j+3], wv.w, acc);
    }
    return acc;
}

template<int N>
__device__ __forceinline__ void ln_vec(float* v, const float* g, const float* b) {
    float m = 0.f;
#pragma unroll
    for (int e = 0; e < N; e++) m += v[e];
    m *= (1.0f / N);
    float var = 0.f;
#pragma unroll
    for (int e = 0; e < N; e++) { float d = v[e] - m; var = fmaf(d, d, var); }
    var *= (1.0f / N);
    float rs = rsqrtf(var + 1e-5f);
#pragma unroll
    for (int e = 0; e < N; e++) v[e] = (v[e] - m) * rs * g[e] + b[e];
}

// ---------------- kernel A: pt-encoder, all-layer LDS weights ----------------
__global__ void __launch_bounds__(NTA)
ptenc_kernel(const float* __restrict__ X,
             const float* __restrict__ Wqkv, const float* __restrict__ bqkv,
             const float* __restrict__ Wo,   const float* __restrict__ bo,
             const float* __restrict__ W1,   const float* __restrict__ b1,
             const float* __restrict__ W2,   const float* __restrict__ b2,
             const float* __restrict__ g1,   const float* __restrict__ be1,
             const float* __restrict__ g2,   const float* __restrict__ be2,
             const float* __restrict__ linW,
             float* __restrict__ part)
{
    __shared__ __align__(16) float pool[8 * BB * 12];   // 12288 B K/V staging, stride 12
    __shared__ __align__(16) float ldsw[NL * LSTR];     // 35072 B all-layer weights

    const int bid = blockIdx.x;
    const int i   = bid >> 2;          // index
    const int blk = bid & 3;           // column-block 0..3
    const int tid = threadIdx.x;
    const int hw  = tid >> 5;          // 0..7
    const int s   = tid & 31;
    const int col = blk * 8 + hw;      // 0..31
    const bool act = (col < SEQL);

    // ---- one-time staging of ALL 4 layers' weights (single barrier) ----
#pragma unroll 1
    for (int l = 0; l < NL; ++l) {
        const size_t po = (size_t)i * NL + l;
        float* wl = ldsw + l * LSTR;
        cp_lds(wl + OWQKV, Wqkv + po * 1200, 1200, tid, NTA);
        cp_lds(wl + OWO,   Wo   + po * 400,  400,  tid, NTA);
        cp_lds(wl + OW1,   W1   + po * 200,  200,  tid, NTA);
        cp_lds(wl + OW2,   W2   + po * 200,  200,  tid, NTA);
        cp_lds(wl + OBQKV, bqkv + po * 60,   60,   tid, NTA);
        cp_lds(wl + OBO,   bo   + po * 20,   20,   tid, NTA);
        cp_lds(wl + OB1,   b1   + po * 10,   10,   tid, NTA);
        cp_lds(wl + OB2,   b2   + po * 20,   20,   tid, NTA);
        cp_lds(wl + OG1,   g1   + po * 20,   20,   tid, NTA);
        cp_lds(wl + OBE1,  be1  + po * 20,   20,   tid, NTA);
        cp_lds(wl + OG2,   g2   + po * 20,   20,   tid, NTA);
        cp_lds(wl + OBE2,  be2  + po * 20,   20,   tid, NTA);
    }
    __syncthreads();

    float x[20];
    if (act) {
        const float4* xr4 = (const float4*)(X + (((size_t)s * NSEQ + i) * SEQL + col) * EMB);
#pragma unroll
        for (int j = 0; j < 5; ++j) {
            float4 t4 = xr4[j];
            x[4*j+0] = t4.x; x[4*j+1] = t4.y; x[4*j+2] = t4.z; x[4*j+3] = t4.w;
        }
#pragma unroll
        for (int j = 0; j < 10; ++j) {
            float div = expf(-0.9210340371976184f * (float)j); // 10000^(-j/10)
            float ang = (float)s * div;
            x[2*j]   += sinf(ang);
            x[2*j+1] += cosf(ang);
        }

        float4* my4 = (float4*)&pool[(hw * BB + s) * 12];
        const float4* kvr4 = (const float4*)&pool[hw * BB * 12];

#pragma unroll 1
        for (int l = 0; l < NL; ++l) {
            const float* wl = ldsw + l * LSTR;

            float out[20];
#pragma unroll
            for (int h = 0; h < NH; ++h) {
                float q[4], k[4], v[4];
#pragma unroll
                for (int d = 0; d < 4; ++d) {
                    const int f = h * 4 + d;   // compile-time after unroll -> imm offsets
                    q[d] = dot20L(x, (const float4*)&wl[OWQKV + f * 20],        wl[OBQKV + f]);
                    k[d] = dot20L(x, (const float4*)&wl[OWQKV + (20 + f) * 20], wl[OBQKV + 20 + f]);
                    v[d] = dot20L(x, (const float4*)&wl[OWQKV + (40 + f) * 20], wl[OBQKV + 40 + f]);
                    q[d] *= 0.72134752044f;    // 0.5 (1/sqrt D) * log2(e)
                }
                // stage k,v (same-wave in-order LDS within a halfwave: no barrier)
                my4[0] = make_float4(k[0], k[1], k[2], k[3]);
                my4[1] = make_float4(v[0], v[1], v[2], v[3]);
                float den = 0.f, o0 = 0.f, o1 = 0.f, o2 = 0.f, o3 = 0.f;
#pragma unroll 4
                for (int t = 0; t < BB; ++t) {
                    float4 kt = kvr4[t * 3 + 0];
                    float4 vt = kvr4[t * 3 + 1];
                    float sc = fmaf(q[0], kt.x, fmaf(q[1], kt.y, fmaf(q[2], kt.z, q[3] * kt.w)));
                    float p = exp2f(sc);
                    den += p;
                    o0 = fmaf(p, vt.x, o0);
                    o1 = fmaf(p, vt.y, o1);
                    o2 = fmaf(p, vt.z, o2);
                    o3 = fmaf(p, vt.w, o3);
                }
                float inv = 1.0f / den;
                out[4*h+0] = o0 * inv;
                out[4*h+1] = o1 * inv;
                out[4*h+2] = o2 * inv;
                out[4*h+3] = o3 * inv;
            }
            float cr[20];
#pragma unroll
            for (int e = 0; e < 20; ++e)
                cr[e] = x[e] + dot20L(out, (const float4*)&wl[OWO + e * 20], wl[OBO + e]);
            ln_vec<20>(cr, &wl[OG1], &wl[OBE1]);
            float hb[FFND];
#pragma unroll
            for (int j = 0; j < FFND; ++j)
                hb[j] = fmaxf(dot20L(cr, (const float4*)&wl[OW1 + j * 20], wl[OB1 + j]), 0.f);
#pragma unroll
            for (int e = 0; e < 20; ++e) {
                const float2* w2 = (const float2*)&wl[OW2 + e * FFND];  // 8B-aligned
                float acc = wl[OB2 + e];
#pragma unroll
                for (int m = 0; m < 5; ++m) {
                    float2 wv = w2[m];
                    acc = fmaf(hb[2*m],   wv.x, acc);
                    acc = fmaf(hb[2*m+1], wv.y, acc);
                }
                x[e] = cr[e] + acc;
            }
            ln_vec<20>(x, &wl[OG2], &wl[OBE2]);
        }

        // lin partials for this column into pool (per-lane-owned slots)
        const float* lwb = linW + (size_t)i * SVS * (SEQL * EMB);
        float* slot = &pool[(hw * BB + s) * 12];
#pragma unroll
        for (int o = 0; o < SVS; ++o) {
            const float* wr = lwb + o * (SEQL * EMB) + col * EMB;
            float acc = 0.f;
#pragma unroll
            for (int j = 0; j < 20; ++j) acc = fmaf(x[j], wr[j], acc);
            slot[o] = acc;
        }
    }
    __syncthreads();

    // block-reduce the (≤8) active columns -> part[i][blk][b][o]  (strided: 320 > 256)
    for (int idx = tid; idx < BB * SVS; idx += NTA) {
        const int b = idx / SVS, o = idx % SVS;
        const int ncols = (blk == 3) ? 1 : 8;
        float acc = 0.f;
        for (int c = 0; c < ncols; ++c) acc += pool[(c * BB + b) * 12 + o];
        part[(((size_t)i * BPI + blk) * BB + b) * SVS + o] = acc;
    }
}

// ---------------- kernel B: lin-bias + st-encoder ----------------
__global__ void __launch_bounds__(NTB)
stenc_kernel(const float* __restrict__ part, const float* __restrict__ linb,
             const float* __restrict__ sWqkv,const float* __restrict__ sbqkv,
             const float* __restrict__ sWo,  const float* __restrict__ sbo,
             const float* __restrict__ sW1,  const float* __restrict__ sb1,
             const float* __restrict__ sW2,  const float* __restrict__ sb2,
             const float* __restrict__ sg1,  const float* __restrict__ sbe1,
             const float* __restrict__ sg2,  const float* __restrict__ sbe2,
             float* __restrict__ sec)
{
    __shared__ float stx[BB][SVS];
    __shared__ float stqkv[BB][3*SVS];
    __shared__ float sttmp[BB][SVS];
    __shared__ float pqW[300], pqB[30], poW[100], poB[10];
    __shared__ float p1W[100], p1B[10], p2W[100], p2B[10];
    __shared__ float pg1[10], pbe1[10], pg2[10], pbe2[10];

    const int i   = blockIdx.x;
    const int tid = threadIdx.x;

    if (tid < BB * SVS) {
        const int b = tid / SVS, o = tid % SVS;
        float acc = linb[i * SVS + o];
#pragma unroll
        for (int blk = 0; blk < BPI; ++blk)
            acc += part[(((size_t)i * BPI + blk) * BB + b) * SVS + o];
        stx[b][o] = acc;
    }

#pragma unroll 1
    for (int l = 0; l < NL; ++l) {
        __syncthreads();
        cp_lds(pqW, sWqkv + l * 300, 300, tid, NTB);
        cp_lds(pqB, sbqkv + l * 30,  30,  tid, NTB);
        cp_lds(poW, sWo   + l * 100, 100, tid, NTB);
        cp_lds(poB, sbo   + l * 10,  10,  tid, NTB);
        cp_lds(p1W, sW1   + l * 100, 100, tid, NTB);
        cp_lds(p1B, sb1   + l * 10,  10,  tid, NTB);
        cp_lds(p2W, sW2   + l * 100, 100, tid, NTB);
        cp_lds(p2B, sb2   + l * 10,  10,  tid, NTB);
        cp_lds(pg1, sg1   + l * 10,  10,  tid, NTB);
        cp_lds(pbe1, sbe1 + l * 10,  10,  tid, NTB);
        cp_lds(pg2, sg2   + l * 10,  10,  tid, NTB);
        cp_lds(pbe2, sbe2 + l * 10,  10,  tid, NTB);
        __syncthreads();

        for (int idx = tid; idx < BB * 3 * SVS; idx += NTB) {   // 960 dots, len 10
            int s2 = idx / (3 * SVS), f = idx % (3 * SVS);
            float acc = pqB[f];
#pragma unroll
            for (int e = 0; e < SVS; e++) acc = fmaf(stx[s2][e], pqW[f * SVS + e], acc);
            stqkv[s2][f] = acc;
        }
        __syncthreads();

        if (tid < BB * NH) {       // attention per (s, h), D=2; single pass
            int s2 = tid / NH, h = tid % NH;
            float q0 = stqkv[s2][h * 2], q1 = stqkv[s2][h * 2 + 1];
            float den = 0.f, o0 = 0.f, o1 = 0.f;
#pragma unroll
            for (int t = 0; t < BB; t++) {
                float d0 = q0 * stqkv[t][SVS + h * 2] + q1 * stqkv[t][SVS + h * 2 + 1];
                float p = __expf(0.70710678118f * d0);
                den += p;
                o0 = fmaf(p, stqkv[t][2 * SVS + h * 2],     o0);
                o1 = fmaf(p, stqkv[t][2 * SVS + h * 2 + 1], o1);
            }
            float inv = 1.0f / den;
            sttmp[s2][h * 2]     = o0 * inv;
            sttmp[s2][h * 2 + 1] = o1 * inv;
        }
        __syncthreads();

        if (tid < BB) {            // proj + LN1 + FFN + LN2, token-local
            int s2 = tid;
            float cr[SVS];
#pragma unroll
            for (int e = 0; e < SVS; e++) {
                float acc = poB[e];
#pragma unroll
                for (int f = 0; f < SVS; f++) acc = fmaf(sttmp[s2][f], poW[e * SVS + f], acc);
                cr[e] = stx[s2][e] + acc;
            }
            ln_vec<SVS>(cr, pg1, pbe1);
            float hb[FFND];
#pragma unroll
            for (int j = 0; j < FFND; j++) {
                float acc = p1B[j];
#pragma unroll
                for (int e = 0; e < SVS; e++) acc = fmaf(cr[e], p1W[j * SVS + e], acc);
                hb[j] = fmaxf(acc, 0.f);
            }
            float fr[SVS];
#pragma unroll
            for (int e = 0; e < SVS; e++) {
                float acc = p2B[e];
#pragma unroll
                for (int j = 0; j < FFND; j++) acc = fmaf(hb[j], p2W[e * FFND + j], acc);
                fr[e] = cr[e] + acc;
            }
            ln_vec<SVS>(fr, pg2, pbe2);
#pragma unroll
            for (int e = 0; e < SVS; e++) stx[s2][e] = fr[e];
        }
        __syncthreads();
    }

    if (tid < BB * SVS) {
        int b = tid / SVS, o = tid % SVS;
        sec[(size_t)b * (NSEQ * SVS) + (size_t)i * SVS + o] = stx[b][o];
    }
}

__global__ __launch_bounds__(256, 1)
void head_kernel(const float* __restrict__ sec,
                 const float* __restrict__ plW, const float* __restrict__ plb,
                 const float* __restrict__ llW, const float* __restrict__ llb,
                 float* __restrict__ out)
{
    const int b = blockIdx.x, tid = threadIdx.x;
    const float* fb = sec + (size_t)b * (NSEQ * SVS);
    float acc[8];
#pragma unroll
    for (int p = 0; p < 8; p++) acc[p] = 0.f;
    for (int f = tid; f < NSEQ * SVS; f += 256) {
        float xv = fb[f];
#pragma unroll
        for (int p = 0; p < 8; p++)
            acc[p] = fmaf(xv, plW[p * (NSEQ * SVS) + f], acc[p]);
    }
#pragma unroll
    for (int p = 0; p < 8; p++) {
#pragma unroll
        for (int off = 32; off > 0; off >>= 1)
            acc[p] += __shfl_down(acc[p], off, 64);
    }
    __shared__ float red[4][8];
    const int wv = tid >> 6, ln = tid & 63;
    if (ln == 0) {
#pragma unroll
        for (int p = 0; p < 8; p++) red[wv][p] = acc[p];
    }
    __syncthreads();
    if (tid == 0) {
        float s8[8];
#pragma unroll
        for (int p = 0; p < 8; p++)
            s8[p] = red[0][p] + red[1][p] + red[2][p] + red[3][p] + plb[p];
#pragma unroll
        for (int qq = 0; qq < 2; qq++) {
            float o = llb[qq];
#pragma unroll
            for (int p = 0; p < 8; p++) o = fmaf(s8[p], llW[qq * 8 + p], o);
            out[b * 2 + qq] = o;
        }
    }
}

extern "C" void kernel_launch(void* const* d_in, const int* in_sizes, int n_in,
                              void* d_out, int out_size, void* d_ws, size_t ws_size,
                              hipStream_t stream)
{
    const float* X     = (const float*)d_in[0];
    const float* Wqkv  = (const float*)d_in[1];
    const float* bqkv  = (const float*)d_in[2];
    const float* Wo    = (const float*)d_in[3];
    const float* bo    = (const float*)d_in[4];
    const float* W1    = (const float*)d_in[5];
    const float* b1    = (const float*)d_in[6];
    const float* W2    = (const float*)d_in[7];
    const float* b2    = (const float*)d_in[8];
    const float* g1    = (const float*)d_in[9];
    const float* be1   = (const float*)d_in[10];
    const float* g2    = (const float*)d_in[11];
    const float* be2   = (const float*)d_in[12];
    const float* linW  = (const float*)d_in[13];
    const float* linb  = (const float*)d_in[14];
    const float* sWqkv = (const float*)d_in[15];
    const float* sbqkv = (const float*)d_in[16];
    const float* sWo   = (const float*)d_in[17];
    const float* sbo   = (const float*)d_in[18];
    const float* sW1   = (const float*)d_in[19];
    const float* sb1   = (const float*)d_in[20];
    const float* sW2   = (const float*)d_in[21];
    const float* sb2   = (const float*)d_in[22];
    const float* sg1   = (const float*)d_in[23];
    const float* sbe1  = (const float*)d_in[24];
    const float* sg2   = (const float*)d_in[25];
    const float* sbe2  = (const float*)d_in[26];
    const float* plW   = (const float*)d_in[27];
    const float* plb   = (const float*)d_in[28];
    const float* llW   = (const float*)d_in[29];
    const float* llb   = (const float*)d_in[30];

    float* part = (float*)d_ws;                         // 430*4*32*10 fp32 = 2,201,600 B
    float* sec  = part + (size_t)NSEQ * BPI * BB * SVS; // 550,400 B more

    ptenc_kernel<<<NSEQ * BPI, NTA, 0, stream>>>(X, Wqkv, bqkv, Wo, bo, W1, b1, W2, b2,
                                                 g1, be1, g2, be2, linW, part);
    stenc_kernel<<<NSEQ, NTB, 0, stream>>>(part, linb,
                                           sWqkv, sbqkv, sWo, sbo, sW1, sb1, sW2, sb2,
                                           sg1, sbe1, sg2, sbe2, sec);
    head_kernel<<<BB, 256, 0, stream>>>(sec, plW, plb, llW, llb, (float*)d_out);
}

// Round 17
// 306.982 us; speedup vs baseline: 1.7438x; 1.3292x over previous
//
#include <hip/hip_runtime.h>
#include <math.h>

#define NSEQ 430
#define SEQL 25
#define EMB  20
#define SVS  10
#define NH   5
#define FFND 10
#define NL   4
#define BB   32           // batch used as sequence axis (S)
#define NTA  256          // kernel A: 4 waves, 8 halfwaves = 8 columns
#define BPI  4            // blocks per index i (8+8+8+1 columns)
#define NTB  320          // kernel B threads

// f16 weight rows padded to 24 elems (48B, 16B-aligned). 90 rows/layer:
//   rows 0..59  = Wqkv, rows 60..79 = Wo, rows 80..89 = W1
#define HROW 24
#define HROWS 90
#define HL   (HROWS*HROW)      // 2160 ushorts per layer
// f32 small region per layer (392 floats):
//   0..199 W2 | 200..259 bqkv | 260..279 bo | 280..289 b1 | 290..309 b2
//   310..329 g1 | 330..349 be1 | 350..369 g2 | 370..389 be2
#define FL   392

typedef _Float16 h2 __attribute__((ext_vector_type(2)));

#define FDOT2(a, b, c) __builtin_amdgcn_fdot2((a), (b), (c), false)

__device__ __forceinline__ void cp_lds(float* dst, const float* src, int n, int tid, int nt) {
    for (int k = tid; k < n; k += nt) dst[k] = src[k];
}

// dot of 12 packed f16 pairs (24 elems incl. zero pad) via v_dot2_f32_f16
__device__ __forceinline__ float dot24h(const h2* xh, const h2* w, float acc) {
#pragma unroll
    for (int j = 0; j < 12; ++j) acc = FDOT2(xh[j], w[j], acc);
    return acc;
}

__device__ __forceinline__ void pack12(h2* dst, const float* src20) {
#pragma unroll
    for (int j = 0; j < 10; ++j) {
        h2 t;
        t.x = (_Float16)src20[2*j];
        t.y = (_Float16)src20[2*j+1];
        dst[j] = t;
    }
    h2 z; z.x = (_Float16)0.f; z.y = (_Float16)0.f;
    dst[10] = z; dst[11] = z;
}

template<int N>
__device__ __forceinline__ void ln_vec(float* v, const float* g, const float* b) {
    float m = 0.f;
#pragma unroll
    for (int e = 0; e < N; e++) m += v[e];
    m *= (1.0f / N);
    float var = 0.f;
#pragma unroll
    for (int e = 0; e < N; e++) { float d = v[e] - m; var = fmaf(d, d, var); }
    var *= (1.0f / N);
    float rs = rsqrtf(var + 1e-5f);
#pragma unroll
    for (int e = 0; e < N; e++) v[e] = (v[e] - m) * rs * g[e] + b[e];
}

// ---------------- kernel A: pt-encoder, f16-dot2 weight matmuls ----------------
__global__ void __launch_bounds__(NTA)
ptenc_kernel(const float* __restrict__ X,
             const float* __restrict__ Wqkv, const float* __restrict__ bqkv,
             const float* __restrict__ Wo,   const float* __restrict__ bo,
             const float* __restrict__ W1,   const float* __restrict__ b1,
             const float* __restrict__ W2,   const float* __restrict__ b2,
             const float* __restrict__ g1,   const float* __restrict__ be1,
             const float* __restrict__ g2,   const float* __restrict__ be2,
             const float* __restrict__ linW,
             float* __restrict__ part)
{
    __shared__ __align__(16) float  pool[8 * BB * 12];   // 12288 B K/V staging
    __shared__ __align__(16) ushort hwgt[NL * HL];       // 17280 B f16 weights
    __shared__ __align__(16) float  fwgt[NL * FL];       // 6272 B f32 smalls

    const int bid = blockIdx.x;
    const int i   = bid >> 2;          // index
    const int blk = bid & 3;           // column-block 0..3
    const int tid = threadIdx.x;
    const int hw  = tid >> 5;          // 0..7
    const int s   = tid & 31;
    const int col = blk * 8 + hw;      // 0..31
    const bool act = (col < SEQL);

    // ---- one-time staging: f16 rows (zero-padded) + f32 smalls ----
    for (int idx = tid; idx < NL * HL; idx += NTA) {
        const int l = idx / HL, rem = idx % HL, r = rem / HROW, c = rem % HROW;
        const size_t po = (size_t)i * NL + l;
        float v = 0.f;
        if (c < 20) {
            if (r < 60)      v = Wqkv[po * 1200 + r * 20 + c];
            else if (r < 80) v = Wo[po * 400 + (r - 60) * 20 + c];
            else             v = W1[po * 200 + (r - 80) * 20 + c];
        }
        _Float16 hv = (_Float16)v;
        hwgt[idx] = *reinterpret_cast<const ushort*>(&hv);
    }
    for (int idx = tid; idx < NL * FL; idx += NTA) {
        const int l = idx / FL, o = idx % FL;
        const size_t po = (size_t)i * NL + l;
        float v;
        if (o < 200)      v = W2[po * 200 + o];
        else if (o < 260) v = bqkv[po * 60 + (o - 200)];
        else if (o < 280) v = bo[po * 20 + (o - 260)];
        else if (o < 290) v = b1[po * 10 + (o - 280)];
        else if (o < 310) v = b2[po * 20 + (o - 290)];
        else if (o < 330) v = g1[po * 20 + (o - 310)];
        else if (o < 350) v = be1[po * 20 + (o - 330)];
        else if (o < 370) v = g2[po * 20 + (o - 350)];
        else              v = be2[po * 20 + (o - 370)];
        fwgt[idx] = v;
    }
    __syncthreads();

    float x[20];
    if (act) {
        const float4* xr4 = (const float4*)(X + (((size_t)s * NSEQ + i) * SEQL + col) * EMB);
#pragma unroll
        for (int j = 0; j < 5; ++j) {
            float4 t4 = xr4[j];
            x[4*j+0] = t4.x; x[4*j+1] = t4.y; x[4*j+2] = t4.z; x[4*j+3] = t4.w;
        }
#pragma unroll
        for (int j = 0; j < 10; ++j) {
            float div = expf(-0.9210340371976184f * (float)j); // 10000^(-j/10)
            float ang = (float)s * div;
            x[2*j]   += sinf(ang);
            x[2*j+1] += cosf(ang);
        }

        float4* my4 = (float4*)&pool[(hw * BB + s) * 12];
        const float4* kvr4 = (const float4*)&pool[hw * BB * 12];

#pragma unroll 1
        for (int l = 0; l < NL; ++l) {
            const h2* wl = (const h2*)&hwgt[l * HL];     // row r at wl + r*12
            const float* fl = &fwgt[l * FL];

            h2 xh[12];
            pack12(xh, x);

            float out[20];
#pragma unroll
            for (int h = 0; h < NH; ++h) {
                float q[4], k[4], v[4];
#pragma unroll
                for (int d = 0; d < 4; ++d) {
                    const int f = h * 4 + d;   // compile-time -> imm LDS offsets
                    q[d] = dot24h(xh, wl + f * 12,        fl[200 + f]) * 0.72134752044f;
                    k[d] = dot24h(xh, wl + (20 + f) * 12, fl[200 + 20 + f]);
                    v[d] = dot24h(xh, wl + (40 + f) * 12, fl[200 + 40 + f]);
                }
                // stage k,v (same-wave in-order LDS within a halfwave: no barrier)
                my4[0] = make_float4(k[0], k[1], k[2], k[3]);
                my4[1] = make_float4(v[0], v[1], v[2], v[3]);
                float den = 0.f, o0 = 0.f, o1 = 0.f, o2 = 0.f, o3 = 0.f;
#pragma unroll 4
                for (int t = 0; t < BB; ++t) {
                    float4 kt = kvr4[t * 3 + 0];
                    float4 vt = kvr4[t * 3 + 1];
                    float sc = fmaf(q[0], kt.x, fmaf(q[1], kt.y, fmaf(q[2], kt.z, q[3] * kt.w)));
                    float p = exp2f(sc);
                    den += p;
                    o0 = fmaf(p, vt.x, o0);
                    o1 = fmaf(p, vt.y, o1);
                    o2 = fmaf(p, vt.z, o2);
                    o3 = fmaf(p, vt.w, o3);
                }
                float inv = 1.0f / den;
                out[4*h+0] = o0 * inv;
                out[4*h+1] = o1 * inv;
                out[4*h+2] = o2 * inv;
                out[4*h+3] = o3 * inv;
            }
            // out-proj + residual + LN1 (f16 dot2)
            h2 oh[12];
            pack12(oh, out);
            float cr[20];
#pragma unroll
            for (int e = 0; e < 20; ++e)
                cr[e] = x[e] + dot24h(oh, wl + (60 + e) * 12, fl[260 + e]);
            ln_vec<20>(cr, fl + 310, fl + 330);
            // FFN1 (f16 dot2) + FFN2 (f32) + residual + LN2
            h2 ch[12];
            pack12(ch, cr);
            float hb[FFND];
#pragma unroll
            for (int j = 0; j < FFND; ++j)
                hb[j] = fmaxf(dot24h(ch, wl + (80 + j) * 12, fl[280 + j]), 0.f);
#pragma unroll
            for (int e = 0; e < 20; ++e) {
                float acc = fl[290 + e];
#pragma unroll
                for (int m = 0; m < FFND; ++m) acc = fmaf(hb[m], fl[e * FFND + m], acc);
                x[e] = cr[e] + acc;
            }
            ln_vec<20>(x, fl + 350, fl + 370);
        }

        // lin partials for this column into pool (f32, per-lane rows)
        const float* lwb = linW + (size_t)i * SVS * (SEQL * EMB);
        float* slot = &pool[(hw * BB + s) * 12];
#pragma unroll
        for (int o = 0; o < SVS; ++o) {
            const float* wr = lwb + o * (SEQL * EMB) + col * EMB;
            float acc = 0.f;
#pragma unroll
            for (int j = 0; j < 20; ++j) acc = fmaf(x[j], wr[j], acc);
            slot[o] = acc;
        }
    }
    __syncthreads();

    // block-reduce the (≤8) active columns -> part[i][blk][b][o]  (strided: 320 > 256)
    for (int idx = tid; idx < BB * SVS; idx += NTA) {
        const int b = idx / SVS, o = idx % SVS;
        const int ncols = (blk == 3) ? 1 : 8;
        float acc = 0.f;
        for (int c = 0; c < ncols; ++c) acc += pool[(c * BB + b) * 12 + o];
        part[(((size_t)i * BPI + blk) * BB + b) * SVS + o] = acc;
    }
}

// ---------------- kernel B: lin-bias + st-encoder ----------------
__global__ void __launch_bounds__(NTB)
stenc_kernel(const float* __restrict__ part, const float* __restrict__ linb,
             const float* __restrict__ sWqkv,const float* __restrict__ sbqkv,
             const float* __restrict__ sWo,  const float* __restrict__ sbo,
             const float* __restrict__ sW1,  const float* __restrict__ sb1,
             const float* __restrict__ sW2,  const float* __restrict__ sb2,
             const float* __restrict__ sg1,  const float* __restrict__ sbe1,
             const float* __restrict__ sg2,  const float* __restrict__ sbe2,
             float* __restrict__ sec)
{
    __shared__ float stx[BB][SVS];
    __shared__ float stqkv[BB][3*SVS];
    __shared__ float sttmp[BB][SVS];
    __shared__ float pqW[300], pqB[30], poW[100], poB[10];
    __shared__ float p1W[100], p1B[10], p2W[100], p2B[10];
    __shared__ float pg1[10], pbe1[10], pg2[10], pbe2[10];

    const int i   = blockIdx.x;
    const int tid = threadIdx.x;

    if (tid < BB * SVS) {
        const int b = tid / SVS, o = tid % SVS;
        float acc = linb[i * SVS + o];
#pragma unroll
        for (int blk = 0; blk < BPI; ++blk)
            acc += part[(((size_t)i * BPI + blk) * BB + b) * SVS + o];
        stx[b][o] = acc;
    }

#pragma unroll 1
    for (int l = 0; l < NL; ++l) {
        __syncthreads();
        cp_lds(pqW, sWqkv + l * 300, 300, tid, NTB);
        cp_lds(pqB, sbqkv + l * 30,  30,  tid, NTB);
        cp_lds(poW, sWo   + l * 100, 100, tid, NTB);
        cp_lds(poB, sbo   + l * 10,  10,  tid, NTB);
        cp_lds(p1W, sW1   + l * 100, 100, tid, NTB);
        cp_lds(p1B, sb1   + l * 10,  10,  tid, NTB);
        cp_lds(p2W, sW2   + l * 100, 100, tid, NTB);
        cp_lds(p2B, sb2   + l * 10,  10,  tid, NTB);
        cp_lds(pg1, sg1   + l * 10,  10,  tid, NTB);
        cp_lds(pbe1, sbe1 + l * 10,  10,  tid, NTB);
        cp_lds(pg2, sg2   + l * 10,  10,  tid, NTB);
        cp_lds(pbe2, sbe2 + l * 10,  10,  tid, NTB);
        __syncthreads();

        for (int idx = tid; idx < BB * 3 * SVS; idx += NTB) {   // 960 dots, len 10
            int s2 = idx / (3 * SVS), f = idx % (3 * SVS);
            float acc = pqB[f];
#pragma unroll
            for (int e = 0; e < SVS; e++) acc = fmaf(stx[s2][e], pqW[f * SVS + e], acc);
            stqkv[s2][f] = acc;
        }
        __syncthreads();

        if (tid < BB * NH) {       // attention per (s, h), D=2; single pass
            int s2 = tid / NH, h = tid % NH;
            float q0 = stqkv[s2][h * 2], q1 = stqkv[s2][h * 2 + 1];
            float den = 0.f, o0 = 0.f, o1 = 0.f;
#pragma unroll
            for (int t = 0; t < BB; t++) {
                float d0 = q0 * stqkv[t][SVS + h * 2] + q1 * stqkv[t][SVS + h * 2 + 1];
                float p = __expf(0.70710678118f * d0);
                den += p;
                o0 = fmaf(p, stqkv[t][2 * SVS + h * 2],     o0);
                o1 = fmaf(p, stqkv[t][2 * SVS + h * 2 + 1], o1);
            }
            float inv = 1.0f / den;
            sttmp[s2][h * 2]     = o0 * inv;
            sttmp[s2][h * 2 + 1] = o1 * inv;
        }
        __syncthreads();

        if (tid < BB) {            // proj + LN1 + FFN + LN2, token-local
            int s2 = tid;
            float cr[SVS];
#pragma unroll
            for (int e = 0; e < SVS; e++) {
                float acc = poB[e];
#pragma unroll
                for (int f = 0; f < SVS; f++) acc = fmaf(sttmp[s2][f], poW[e * SVS + f], acc);
                cr[e] = stx[s2][e] + acc;
            }
            ln_vec<SVS>(cr, pg1, pbe1);
            float hb[FFND];
#pragma unroll
            for (int j = 0; j < FFND; j++) {
                float acc = p1B[j];
#pragma unroll
                for (int e = 0; e < SVS; e++) acc = fmaf(cr[e], p1W[j * SVS + e], acc);
                hb[j] = fmaxf(acc, 0.f);
            }
            float fr[SVS];
#pragma unroll
            for (int e = 0; e < SVS; e++) {
                float acc = p2B[e];
#pragma unroll
                for (int j = 0; j < FFND; j++) acc = fmaf(hb[j], p2W[e * FFND + j], acc);
                fr[e] = cr[e] + acc;
            }
            ln_vec<SVS>(fr, pg2, pbe2);
#pragma unroll
            for (int e = 0; e < SVS; e++) stx[s2][e] = fr[e];
        }
        __syncthreads();
    }

    if (tid < BB * SVS) {
        int b = tid / SVS, o = tid % SVS;
        sec[(size_t)b * (NSEQ * SVS) + (size_t)i * SVS + o] = stx[b][o];
    }
}

__global__ __launch_bounds__(256, 1)
void head_kernel(const float* __restrict__ sec,
                 const float* __restrict__ plW, const float* __restrict__ plb,
                 const float* __restrict__ llW, const float* __restrict__ llb,
                 float* __restrict__ out)
{
    const int b = blockIdx.x, tid = threadIdx.x;
    const float* fb = sec + (size_t)b * (NSEQ * SVS);
    float acc[8];
#pragma unroll
    for (int p = 0; p < 8; p++) acc[p] = 0.f;
    for (int f = tid; f < NSEQ * SVS; f += 256) {
        float xv = fb[f];
#pragma unroll
        for (int p = 0; p < 8; p++)
            acc[p] = fmaf(xv, plW[p * (NSEQ * SVS) + f], acc[p]);
    }
#pragma unroll
    for (int p = 0; p < 8; p++) {
#pragma unroll
        for (int off = 32; off > 0; off >>= 1)
            acc[p] += __shfl_down(acc[p], off, 64);
    }
    __shared__ float red[4][8];
    const int wv = tid >> 6, ln = tid & 63;
    if (ln == 0) {
#pragma unroll
        for (int p = 0; p < 8; p++) red[wv][p] = acc[p];
    }
    __syncthreads();
    if (tid == 0) {
        float s8[8];
#pragma unroll
        for (int p = 0; p < 8; p++)
            s8[p] = red[0][p] + red[1][p] + red[2][p] + red[3][p] + plb[p];
#pragma unroll
        for (int qq = 0; qq < 2; qq++) {
            float o = llb[qq];
#pragma unroll
            for (int p = 0; p < 8; p++) o = fmaf(s8[p], llW[qq * 8 + p], o);
            out[b * 2 + qq] = o;
        }
    }
}

extern "C" void kernel_launch(void* const* d_in, const int* in_sizes, int n_in,
                              void* d_out, int out_size, void* d_ws, size_t ws_size,
                              hipStream_t stream)
{
    const float* X     = (const float*)d_in[0];
    const float* Wqkv  = (const float*)d_in[1];
    const float* bqkv  = (const float*)d_in[2];
    const float* Wo    = (const float*)d_in[3];
    const float* bo    = (const float*)d_in[4];
    const float* W1    = (const float*)d_in[5];
    const float* b1    = (const float*)d_in[6];
    const float* W2    = (const float*)d_in[7];
    const float* b2    = (const float*)d_in[8];
    const float* g1    = (const float*)d_in[9];
    const float* be1   = (const float*)d_in[10];
    const float* g2    = (const float*)d_in[11];
    const float* be2   = (const float*)d_in[12];
    const float* linW  = (const float*)d_in[13];
    const float* linb  = (const float*)d_in[14];
    const float* sWqkv = (const float*)d_in[15];
    const float* sbqkv = (const float*)d_in[16];
    const float* sWo   = (const float*)d_in[17];
    const float* sbo   = (const float*)d_in[18];
    const float* sW1   = (const float*)d_in[19];
    const float* sb1   = (const float*)d_in[20];
    const float* sW2   = (const float*)d_in[21];
    const float* sb2   = (const float*)d_in[22];
    const float* sg1   = (const float*)d_in[23];
    const float* sbe1  = (const float*)d_in[24];
    const float* sg2   = (const float*)d_in[25];
    const float* sbe2  = (const float*)d_in[26];
    const float* plW   = (const float*)d_in[27];
    const float* plb   = (const float*)d_in[28];
    const float* llW   = (const float*)d_in[29];
    const float* llb   = (const float*)d_in[30];

    float* part = (float*)d_ws;                         // 430*4*32*10 fp32 = 2,201,600 B
    float* sec  = part + (size_t)NSEQ * BPI * BB * SVS; // 550,400 B more

    ptenc_kernel<<<NSEQ * BPI, NTA, 0, stream>>>(X, Wqkv, bqkv, Wo, bo, W1, b1, W2, b2,
                                                 g1, be1, g2, be2, linW, part);
    stenc_kernel<<<NSEQ, NTB, 0, stream>>>(part, linb,
                                           sWqkv, sbqkv, sWo, sbo, sW1, sb1, sW2, sb2,
                                           sg1, sbe1, sg2, sbe2, sec);
    head_kernel<<<BB, 256, 0, stream>>>(sec, plW, plb, llW, llb, (float*)d_out);
}

// Round 18
// 303.782 us; speedup vs baseline: 1.7621x; 1.0105x over previous
//
#include <hip/hip_runtime.h>
#include <math.h>

#define NSEQ 430
#define SEQL 25
#define EMB  20
#define SVS  10
#define NH   5
#define FFND 10
#define NL   4
#define BB   32           // batch used as sequence axis (S)
#define NTA  256          // kernel A: 4 waves, 8 halfwaves = 8 columns
#define BPI  4            // blocks per index i (8+8+8+1 columns)
#define NTB  320          // kernel B threads

// f16 weight rows padded to 24 elems (48B, 16B-aligned). 90 rows/layer:
//   rows 0..59  = Wqkv, rows 60..79 = Wo, rows 80..89 = W1
#define HROW 24
#define HROWS 90
#define HL   (HROWS*HROW)      // 2160 ushorts per layer
// f32 small region per layer (392 floats):
//   0..199 W2 | 200..259 bqkv | 260..279 bo | 280..289 b1 | 290..309 b2
//   310..329 g1 | 330..349 be1 | 350..369 g2 | 370..389 be2
#define FL   392

typedef _Float16 h2 __attribute__((ext_vector_type(2)));

#define FDOT2(a, b, c) __builtin_amdgcn_fdot2((a), (b), (c), false)

__device__ __forceinline__ void cp_lds(float* dst, const float* src, int n, int tid, int nt) {
    for (int k = tid; k < n; k += nt) dst[k] = src[k];
}

// dot of 12 packed f16 pairs (24 elems incl. zero pad) via v_dot2_f32_f16
__device__ __forceinline__ float dot24h(const h2* xh, const h2* w, float acc) {
#pragma unroll
    for (int j = 0; j < 12; ++j) acc = FDOT2(xh[j], w[j], acc);
    return acc;
}

__device__ __forceinline__ void pack12(h2* dst, const float* src20) {
#pragma unroll
    for (int j = 0; j < 10; ++j) {
        h2 t;
        t.x = (_Float16)src20[2*j];
        t.y = (_Float16)src20[2*j+1];
        dst[j] = t;
    }
    h2 z; z.x = (_Float16)0.f; z.y = (_Float16)0.f;
    dst[10] = z; dst[11] = z;
}

__device__ __forceinline__ unsigned int h2bits(float a, float b) {
    h2 t; t.x = (_Float16)a; t.y = (_Float16)b;
    return __builtin_bit_cast(unsigned int, t);
}

template<int N>
__device__ __forceinline__ void ln_vec(float* v, const float* g, const float* b) {
    float m = 0.f;
#pragma unroll
    for (int e = 0; e < N; e++) m += v[e];
    m *= (1.0f / N);
    float var = 0.f;
#pragma unroll
    for (int e = 0; e < N; e++) { float d = v[e] - m; var = fmaf(d, d, var); }
    var *= (1.0f / N);
    float rs = rsqrtf(var + 1e-5f);
#pragma unroll
    for (int e = 0; e < N; e++) v[e] = (v[e] - m) * rs * g[e] + b[e];
}

// ---------------- kernel A: pt-encoder, f16 everywhere hot ----------------
__global__ void __launch_bounds__(NTA)
ptenc_kernel(const float* __restrict__ X,
             const float* __restrict__ Wqkv, const float* __restrict__ bqkv,
             const float* __restrict__ Wo,   const float* __restrict__ bo,
             const float* __restrict__ W1,   const float* __restrict__ b1,
             const float* __restrict__ W2,   const float* __restrict__ b2,
             const float* __restrict__ g1,   const float* __restrict__ be1,
             const float* __restrict__ g2,   const float* __restrict__ be2,
             const float* __restrict__ linW,
             float* __restrict__ part)
{
    __shared__ __align__(16) float  pool[8 * BB * 12];   // 12288 B kv(f16,16B)/lin(f32)
    __shared__ __align__(16) ushort hwgt[NL * HL];       // 17280 B f16 weights
    __shared__ __align__(16) float  fwgt[NL * FL];       // 6272 B f32 smalls

    const int bid = blockIdx.x;
    const int i   = bid >> 2;          // index
    const int blk = bid & 3;           // column-block 0..3
    const int tid = threadIdx.x;
    const int hw  = tid >> 5;          // 0..7
    const int s   = tid & 31;
    const int col = blk * 8 + hw;      // 0..31
    const bool act = (col < SEQL);

    // ---- one-time staging: f16 rows (zero-padded) + f32 smalls ----
    for (int idx = tid; idx < NL * HL; idx += NTA) {
        const int l = idx / HL, rem = idx % HL, r = rem / HROW, c = rem % HROW;
        const size_t po = (size_t)i * NL + l;
        float v = 0.f;
        if (c < 20) {
            if (r < 60)      v = Wqkv[po * 1200 + r * 20 + c];
            else if (r < 80) v = Wo[po * 400 + (r - 60) * 20 + c];
            else             v = W1[po * 200 + (r - 80) * 20 + c];
        }
        _Float16 hv = (_Float16)v;
        hwgt[idx] = *reinterpret_cast<const ushort*>(&hv);
    }
    for (int idx = tid; idx < NL * FL; idx += NTA) {
        const int l = idx / FL, o = idx % FL;
        const size_t po = (size_t)i * NL + l;
        float v;
        if (o < 200)      v = W2[po * 200 + o];
        else if (o < 260) v = bqkv[po * 60 + (o - 200)];
        else if (o < 280) v = bo[po * 20 + (o - 260)];
        else if (o < 290) v = b1[po * 10 + (o - 280)];
        else if (o < 310) v = b2[po * 20 + (o - 290)];
        else if (o < 330) v = g1[po * 20 + (o - 310)];
        else if (o < 350) v = be1[po * 20 + (o - 330)];
        else if (o < 370) v = g2[po * 20 + (o - 350)];
        else              v = be2[po * 20 + (o - 370)];
        fwgt[idx] = v;
    }
    __syncthreads();

    float x[20];
    if (act) {
        const float4* xr4 = (const float4*)(X + (((size_t)s * NSEQ + i) * SEQL + col) * EMB);
#pragma unroll
        for (int j = 0; j < 5; ++j) {
            float4 t4 = xr4[j];
            x[4*j+0] = t4.x; x[4*j+1] = t4.y; x[4*j+2] = t4.z; x[4*j+3] = t4.w;
        }
#pragma unroll
        for (int j = 0; j < 10; ++j) {
            float div = expf(-0.9210340371976184f * (float)j); // 10000^(-j/10)
            float ang = (float)s * div;
            x[2*j]   += sinf(ang);
            x[2*j+1] += cosf(ang);
        }

        uint4* mykv = (uint4*)&pool[(hw * BB + s) * 12];        // 16B f16 kv slot
        const uint4* kvr = (const uint4*)&pool[hw * BB * 12];   // slot t at kvr[t*3]

#pragma unroll 1
        for (int l = 0; l < NL; ++l) {
            const h2* wl = (const h2*)&hwgt[l * HL];     // row r at wl + r*12
            const float* fl = &fwgt[l * FL];

            h2 xh[12];
            pack12(xh, x);

            float out[20];
#pragma unroll
            for (int h = 0; h < NH; ++h) {
                float q[4], k[4], v[4];
#pragma unroll
                for (int d = 0; d < 4; ++d) {
                    const int f = h * 4 + d;   // compile-time -> imm LDS offsets
                    q[d] = dot24h(xh, wl + f * 12,        fl[200 + f]) * 0.72134752044f;
                    k[d] = dot24h(xh, wl + (20 + f) * 12, fl[200 + 20 + f]);
                    v[d] = dot24h(xh, wl + (40 + f) * 12, fl[200 + 40 + f]);
                }
                // stage k,v as f16 in ONE 16B write (same-wave lockstep: no barrier)
                uint4 pk;
                pk.x = h2bits(k[0], k[1]);
                pk.y = h2bits(k[2], k[3]);
                pk.z = h2bits(v[0], v[1]);
                pk.w = h2bits(v[2], v[3]);
                *mykv = pk;
                // q packed f16 for the score fdot2
                h2 q01 = __builtin_bit_cast(h2, h2bits(q[0], q[1]));
                h2 q23 = __builtin_bit_cast(h2, h2bits(q[2], q[3]));
                float den = 0.f;
                h2 o01; o01.x = (_Float16)0.f; o01.y = (_Float16)0.f;
                h2 o23 = o01;
#pragma unroll 4
                for (int t = 0; t < BB; ++t) {
                    uint4 kv = kvr[t * 3];
                    h2 klo = __builtin_bit_cast(h2, kv.x);
                    h2 khi = __builtin_bit_cast(h2, kv.y);
                    h2 vlo = __builtin_bit_cast(h2, kv.z);
                    h2 vhi = __builtin_bit_cast(h2, kv.w);
                    float sc = FDOT2(q01, klo, FDOT2(q23, khi, 0.f));
                    float p = exp2f(sc);
                    den += p;
                    _Float16 ph = (_Float16)p;
                    h2 pp; pp.x = ph; pp.y = ph;
                    o01 = pp * vlo + o01;    // v_pk_fma_f16
                    o23 = pp * vhi + o23;
                }
                float inv = 1.0f / den;
                out[4*h+0] = (float)o01.x * inv;
                out[4*h+1] = (float)o01.y * inv;
                out[4*h+2] = (float)o23.x * inv;
                out[4*h+3] = (float)o23.y * inv;
            }
            // out-proj + residual + LN1 (f16 dot2)
            h2 oh[12];
            pack12(oh, out);
            float cr[20];
#pragma unroll
            for (int e = 0; e < 20; ++e)
                cr[e] = x[e] + dot24h(oh, wl + (60 + e) * 12, fl[260 + e]);
            ln_vec<20>(cr, fl + 310, fl + 330);
            // FFN1 (f16 dot2) + FFN2 (f32) + residual + LN2
            h2 ch[12];
            pack12(ch, cr);
            float hb[FFND];
#pragma unroll
            for (int j = 0; j < FFND; ++j)
                hb[j] = fmaxf(dot24h(ch, wl + (80 + j) * 12, fl[280 + j]), 0.f);
#pragma unroll
            for (int e = 0; e < 20; ++e) {
                float acc = fl[290 + e];
#pragma unroll
                for (int m = 0; m < FFND; ++m) acc = fmaf(hb[m], fl[e * FFND + m], acc);
                x[e] = cr[e] + acc;
            }
            ln_vec<20>(x, fl + 350, fl + 370);
        }

        // lin partials for this column into pool (f32, per-lane rows)
        const float* lwb = linW + (size_t)i * SVS * (SEQL * EMB);
        float* slot = &pool[(hw * BB + s) * 12];
#pragma unroll
        for (int o = 0; o < SVS; ++o) {
            const float* wr = lwb + o * (SEQL * EMB) + col * EMB;
            float acc = 0.f;
#pragma unroll
            for (int j = 0; j < 20; ++j) acc = fmaf(x[j], wr[j], acc);
            slot[o] = acc;
        }
    }
    __syncthreads();

    // block-reduce the (≤8) active columns -> part[i][blk][b][o]  (strided: 320 > 256)
    for (int idx = tid; idx < BB * SVS; idx += NTA) {
        const int b = idx / SVS, o = idx % SVS;
        const int ncols = (blk == 3) ? 1 : 8;
        float acc = 0.f;
        for (int c = 0; c < ncols; ++c) acc += pool[(c * BB + b) * 12 + o];
        part[(((size_t)i * BPI + blk) * BB + b) * SVS + o] = acc;
    }
}

// ---------------- kernel B: lin-bias + st-encoder ----------------
__global__ void __launch_bounds__(NTB)
stenc_kernel(const float* __restrict__ part, const float* __restrict__ linb,
             const float* __restrict__ sWqkv,const float* __restrict__ sbqkv,
             const float* __restrict__ sWo,  const float* __restrict__ sbo,
             const float* __restrict__ sW1,  const float* __restrict__ sb1,
             const float* __restrict__ sW2,  const float* __restrict__ sb2,
             const float* __restrict__ sg1,  const float* __restrict__ sbe1,
             const float* __restrict__ sg2,  const float* __restrict__ sbe2,
             float* __restrict__ sec)
{
    __shared__ float stx[BB][SVS];
    __shared__ float stqkv[BB][3*SVS];
    __shared__ float sttmp[BB][SVS];
    __shared__ float pqW[300], pqB[30], poW[100], poB[10];
    __shared__ float p1W[100], p1B[10], p2W[100], p2B[10];
    __shared__ float pg1[10], pbe1[10], pg2[10], pbe2[10];

    const int i   = blockIdx.x;
    const int tid = threadIdx.x;

    if (tid < BB * SVS) {
        const int b = tid / SVS, o = tid % SVS;
        float acc = linb[i * SVS + o];
#pragma unroll
        for (int blk = 0; blk < BPI; ++blk)
            acc += part[(((size_t)i * BPI + blk) * BB + b) * SVS + o];
        stx[b][o] = acc;
    }

#pragma unroll 1
    for (int l = 0; l < NL; ++l) {
        __syncthreads();
        cp_lds(pqW, sWqkv + l * 300, 300, tid, NTB);
        cp_lds(pqB, sbqkv + l * 30,  30,  tid, NTB);
        cp_lds(poW, sWo   + l * 100, 100, tid, NTB);
        cp_lds(poB, sbo   + l * 10,  10,  tid, NTB);
        cp_lds(p1W, sW1   + l * 100, 100, tid, NTB);
        cp_lds(p1B, sb1   + l * 10,  10,  tid, NTB);
        cp_lds(p2W, sW2   + l * 100, 100, tid, NTB);
        cp_lds(p2B, sb2   + l * 10,  10,  tid, NTB);
        cp_lds(pg1, sg1   + l * 10,  10,  tid, NTB);
        cp_lds(pbe1, sbe1 + l * 10,  10,  tid, NTB);
        cp_lds(pg2, sg2   + l * 10,  10,  tid, NTB);
        cp_lds(pbe2, sbe2 + l * 10,  10,  tid, NTB);
        __syncthreads();

        for (int idx = tid; idx < BB * 3 * SVS; idx += NTB) {   // 960 dots, len 10
            int s2 = idx / (3 * SVS), f = idx % (3 * SVS);
            float acc = pqB[f];
#pragma unroll
            for (int e = 0; e < SVS; e++) acc = fmaf(stx[s2][e], pqW[f * SVS + e], acc);
            stqkv[s2][f] = acc;
        }
        __syncthreads();

        if (tid < BB * NH) {       // attention per (s, h), D=2; single pass
            int s2 = tid / NH, h = tid % NH;
            float q0 = stqkv[s2][h * 2], q1 = stqkv[s2][h * 2 + 1];
            float den = 0.f, o0 = 0.f, o1 = 0.f;
#pragma unroll
            for (int t = 0; t < BB; t++) {
                float d0 = q0 * stqkv[t][SVS + h * 2] + q1 * stqkv[t][SVS + h * 2 + 1];
                float p = __expf(0.70710678118f * d0);
                den += p;
                o0 = fmaf(p, stqkv[t][2 * SVS + h * 2],     o0);
                o1 = fmaf(p, stqkv[t][2 * SVS + h * 2 + 1], o1);
            }
            float inv = 1.0f / den;
            sttmp[s2][h * 2]     = o0 * inv;
            sttmp[s2][h * 2 + 1] = o1 * inv;
        }
        __syncthreads();

        if (tid < BB) {            // proj + LN1 + FFN + LN2, token-local
            int s2 = tid;
            float cr[SVS];
#pragma unroll
            for (int e = 0; e < SVS; e++) {
                float acc = poB[e];
#pragma unroll
                for (int f = 0; f < SVS; f++) acc = fmaf(sttmp[s2][f], poW[e * SVS + f], acc);
                cr[e] = stx[s2][e] + acc;
            }
            ln_vec<SVS>(cr, pg1, pbe1);
            float hb[FFND];
#pragma unroll
            for (int j = 0; j < FFND; j++) {
                float acc = p1B[j];
#pragma unroll
                for (int e = 0; e < SVS; e++) acc = fmaf(cr[e], p1W[j * SVS + e], acc);
                hb[j] = fmaxf(acc, 0.f);
            }
            float fr[SVS];
#pragma unroll
            for (int e = 0; e < SVS; e++) {
                float acc = p2B[e];
#pragma unroll
                for (int j = 0; j < FFND; j++) acc = fmaf(hb[j], p2W[e * FFND + j], acc);
                fr[e] = cr[e] + acc;
            }
            ln_vec<SVS>(fr, pg2, pbe2);
#pragma unroll
            for (int e = 0; e < SVS; e++) stx[s2][e] = fr[e];
        }
        __syncthreads();
    }

    if (tid < BB * SVS) {
        int b = tid / SVS, o = tid % SVS;
        sec[(size_t)b * (NSEQ * SVS) + (size_t)i * SVS + o] = stx[b][o];
    }
}

__global__ __launch_bounds__(256, 1)
void head_kernel(const float* __restrict__ sec,
                 const float* __restrict__ plW, const float* __restrict__ plb,
                 const float* __restrict__ llW, const float* __restrict__ llb,
                 float* __restrict__ out)
{
    const int b = blockIdx.x, tid = threadIdx.x;
    const float* fb = sec + (size_t)b * (NSEQ * SVS);
    float acc[8];
#pragma unroll
    for (int p = 0; p < 8; p++) acc[p] = 0.f;
    for (int f = tid; f < NSEQ * SVS; f += 256) {
        float xv = fb[f];
#pragma unroll
        for (int p = 0; p < 8; p++)
            acc[p] = fmaf(xv, plW[p * (NSEQ * SVS) + f], acc[p]);
    }
#pragma unroll
    for (int p = 0; p < 8; p++) {
#pragma unroll
        for (int off = 32; off > 0; off >>= 1)
            acc[p] += __shfl_down(acc[p], off, 64);
    }
    __shared__ float red[4][8];
    const int wv = tid >> 6, ln = tid & 63;
    if (ln == 0) {
#pragma unroll
        for (int p = 0; p < 8; p++) red[wv][p] = acc[p];
    }
    __syncthreads();
    if (tid == 0) {
        float s8[8];
#pragma unroll
        for (int p = 0; p < 8; p++)
            s8[p] = red[0][p] + red[1][p] + red[2][p] + red[3][p] + plb[p];
#pragma unroll
        for (int qq = 0; qq < 2; qq++) {
            float o = llb[qq];
#pragma unroll
            for (int p = 0; p < 8; p++) o = fmaf(s8[p], llW[qq * 8 + p], o);
            out[b * 2 + qq] = o;
        }
    }
}

extern "C" void kernel_launch(void* const* d_in, const int* in_sizes, int n_in,
                              void* d_out, int out_size, void* d_ws, size_t ws_size,
                              hipStream_t stream)
{
    const float* X     = (const float*)d_in[0];
    const float* Wqkv  = (const float*)d_in[1];
    const float* bqkv  = (const float*)d_in[2];
    const float* Wo    = (const float*)d_in[3];
    const float* bo    = (const float*)d_in[4];
    const float* W1    = (const float*)d_in[5];
    const float* b1    = (const float*)d_in[6];
    const float* W2    = (const float*)d_in[7];
    const float* b2    = (const float*)d_in[8];
    const float* g1    = (const float*)d_in[9];
    const float* be1   = (const float*)d_in[10];
    const float* g2    = (const float*)d_in[11];
    const float* be2   = (const float*)d_in[12];
    const float* linW  = (const float*)d_in[13];
    const float* linb  = (const float*)d_in[14];
    const float* sWqkv = (const float*)d_in[15];
    const float* sbqkv = (const float*)d_in[16];
    const float* sWo   = (const float*)d_in[17];
    const float* sbo   = (const float*)d_in[18];
    const float* sW1   = (const float*)d_in[19];
    const float* sb1   = (const float*)d_in[20];
    const float* sW2   = (const float*)d_in[21];
    const float* sb2   = (const float*)d_in[22];
    const float* sg1   = (const float*)d_in[23];
    const float* sbe1  = (const float*)d_in[24];
    const float* sg2   = (const float*)d_in[25];
    const float* sbe2  = (const float*)d_in[26];
    const float* plW   = (const float*)d_in[27];
    const float* plb   = (const float*)d_in[28];
    const float* llW   = (const float*)d_in[29];
    const float* llb   = (const float*)d_in[30];

    float* part = (float*)d_ws;                         // 430*4*32*10 fp32 = 2,201,600 B
    float* sec  = part + (size_t)NSEQ * BPI * BB * SVS; // 550,400 B more

    ptenc_kernel<<<NSEQ * BPI, NTA, 0, stream>>>(X, Wqkv, bqkv, Wo, bo, W1, b1, W2, b2,
                                                 g1, be1, g2, be2, linW, part);
    stenc_kernel<<<NSEQ, NTB, 0, stream>>>(part, linb,
                                           sWqkv, sbqkv, sWo, sbo, sW1, sb1, sW2, sb2,
                                           sg1, sbe1, sg2, sbe2, sec);
    head_kernel<<<BB, 256, 0, stream>>>(sec, plW, plb, llW, llb, (float*)d_out);
}

// Round 19
// 299.895 us; speedup vs baseline: 1.7850x; 1.0130x over previous
//
#include <hip/hip_runtime.h>
#include <math.h>

#define NSEQ 430
#define SEQL 25
#define EMB  20
#define SVS  10
#define NH   5
#define FFND 10
#define NL   4
#define BB   32           // batch used as sequence axis (S)
#define NTA  256          // kernel A: 4 waves, 8 halfwaves = 8 columns
#define BPI  4            // blocks per index i (8+8+8+1 columns)
#define NTB  320          // kernel B threads

// f16 weight rows padded to 24 elems (48B, 16B-aligned). 90 rows/layer:
//   rows 0..59  = Wqkv, rows 60..79 = Wo, rows 80..89 = W1
#define HROW 24
#define HROWS 90
#define HL   (HROWS*HROW)      // 2160 ushorts per layer
// f32 small region per layer (392 floats):
//   0..199 W2 | 200..259 bqkv | 260..279 bo | 280..289 b1 | 290..309 b2
//   310..329 g1 | 330..349 be1 | 350..369 g2 | 370..389 be2
#define FL   392

typedef _Float16 h2 __attribute__((ext_vector_type(2)));

#define FDOT2(a, b, c) __builtin_amdgcn_fdot2((a), (b), (c), false)

__device__ __forceinline__ h2 bch2(unsigned int u) { return __builtin_bit_cast(h2, u); }

__device__ __forceinline__ void cp_lds(float* dst, const float* src, int n, int tid, int nt) {
    for (int k = tid; k < n; k += nt) dst[k] = src[k];
}

// dot of 12 packed f16 pairs (24 elems incl. zero pad) via v_dot2_f32_f16
__device__ __forceinline__ float dot24h(const h2* xh, const h2* w, float acc) {
#pragma unroll
    for (int j = 0; j < 12; ++j) acc = FDOT2(xh[j], w[j], acc);
    return acc;
}

__device__ __forceinline__ void pack12(h2* dst, const float* src20) {
#pragma unroll
    for (int j = 0; j < 10; ++j) {
        h2 t;
        t.x = (_Float16)src20[2*j];
        t.y = (_Float16)src20[2*j+1];
        dst[j] = t;
    }
    h2 z; z.x = (_Float16)0.f; z.y = (_Float16)0.f;
    dst[10] = z; dst[11] = z;
}

__device__ __forceinline__ unsigned int h2bits(float a, float b) {
    h2 t; t.x = (_Float16)a; t.y = (_Float16)b;
    return __builtin_bit_cast(unsigned int, t);
}

template<int N>
__device__ __forceinline__ void ln_vec(float* v, const float* g, const float* b) {
    float m = 0.f;
#pragma unroll
    for (int e = 0; e < N; e++) m += v[e];
    m *= (1.0f / N);
    float var = 0.f;
#pragma unroll
    for (int e = 0; e < N; e++) { float d = v[e] - m; var = fmaf(d, d, var); }
    var *= (1.0f / N);
    float rs = rsqrtf(var + 1e-5f);
#pragma unroll
    for (int e = 0; e < N; e++) v[e] = (v[e] - m) * rs * g[e] + b[e];
}

// ---------------- kernel A: pt-encoder, f16 + key-pair t-loop ----------------
__global__ void __launch_bounds__(NTA)
ptenc_kernel(const float* __restrict__ X,
             const float* __restrict__ Wqkv, const float* __restrict__ bqkv,
             const float* __restrict__ Wo,   const float* __restrict__ bo,
             const float* __restrict__ W1,   const float* __restrict__ b1,
             const float* __restrict__ W2,   const float* __restrict__ b2,
             const float* __restrict__ g1,   const float* __restrict__ be1,
             const float* __restrict__ g2,   const float* __restrict__ be2,
             const float* __restrict__ linW,
             float* __restrict__ part)
{
    // pool slot (hw,s): stride 12 floats (48B, 16B-aligned).
    //   floats [0..1]: K (4 f16)      — written by lane s
    //   floats [4..7] of EVEN slots:  V pair-interleaved (h2 d = (v_even[d], v_odd[d]))
    //   floats [0..9]: lin partials   — after all layers (wave-lockstep safe)
    __shared__ __align__(16) float  pool[8 * BB * 12];   // 12288 B
    __shared__ __align__(16) ushort hwgt[NL * HL];       // 17280 B f16 weights
    __shared__ __align__(16) float  fwgt[NL * FL];       // 6272 B f32 smalls

    const int bid = blockIdx.x;
    const int i   = bid >> 2;          // index
    const int blk = bid & 3;           // column-block 0..3
    const int tid = threadIdx.x;
    const int hw  = tid >> 5;          // 0..7
    const int s   = tid & 31;
    const int col = blk * 8 + hw;      // 0..31
    const bool act = (col < SEQL);

    // ---- one-time staging: f16 rows (zero-padded) + f32 smalls ----
    for (int idx = tid; idx < NL * HL; idx += NTA) {
        const int l = idx / HL, rem = idx % HL, r = rem / HROW, c = rem % HROW;
        const size_t po = (size_t)i * NL + l;
        float v = 0.f;
        if (c < 20) {
            if (r < 60)      v = Wqkv[po * 1200 + r * 20 + c];
            else if (r < 80) v = Wo[po * 400 + (r - 60) * 20 + c];
            else             v = W1[po * 200 + (r - 80) * 20 + c];
        }
        _Float16 hv = (_Float16)v;
        hwgt[idx] = *reinterpret_cast<const ushort*>(&hv);
    }
    for (int idx = tid; idx < NL * FL; idx += NTA) {
        const int l = idx / FL, o = idx % FL;
        const size_t po = (size_t)i * NL + l;
        float v;
        if (o < 200)      v = W2[po * 200 + o];
        else if (o < 260) v = bqkv[po * 60 + (o - 200)];
        else if (o < 280) v = bo[po * 20 + (o - 260)];
        else if (o < 290) v = b1[po * 10 + (o - 280)];
        else if (o < 310) v = b2[po * 20 + (o - 290)];
        else if (o < 330) v = g1[po * 20 + (o - 310)];
        else if (o < 350) v = be1[po * 20 + (o - 330)];
        else if (o < 370) v = g2[po * 20 + (o - 350)];
        else              v = be2[po * 20 + (o - 370)];
        fwgt[idx] = v;
    }
    __syncthreads();

    float x[20];
    if (act) {
        const float4* xr4 = (const float4*)(X + (((size_t)s * NSEQ + i) * SEQL + col) * EMB);
#pragma unroll
        for (int j = 0; j < 5; ++j) {
            float4 t4 = xr4[j];
            x[4*j+0] = t4.x; x[4*j+1] = t4.y; x[4*j+2] = t4.z; x[4*j+3] = t4.w;
        }
#pragma unroll
        for (int j = 0; j < 10; ++j) {
            float div = expf(-0.9210340371976184f * (float)j); // 10000^(-j/10)
            float ang = (float)s * div;
            x[2*j]   += sinf(ang);
            x[2*j+1] += cosf(ang);
        }

        float* myK = &pool[(hw * BB + s) * 12];                  // 8B K slot
        ushort* myV = (ushort*)&pool[(hw * BB + (s & ~1)) * 12 + 4]; // pair V region
        const int vlane = s & 1;
        const float* hwbase = &pool[hw * BB * 12];

        h2 ones; ones.x = (_Float16)1.f; ones.y = (_Float16)1.f;

#pragma unroll 1
        for (int l = 0; l < NL; ++l) {
            const h2* wl = (const h2*)&hwgt[l * HL];     // row r at wl + r*12
            const float* fl = &fwgt[l * FL];

            h2 xh[12];
            pack12(xh, x);

            float out[20];
#pragma unroll
            for (int h = 0; h < NH; ++h) {
                float q[4], k[4], v[4];
#pragma unroll
                for (int d = 0; d < 4; ++d) {
                    const int f = h * 4 + d;   // compile-time -> imm LDS offsets
                    q[d] = dot24h(xh, wl + f * 12,        fl[200 + f]) * 0.72134752044f;
                    k[d] = dot24h(xh, wl + (20 + f) * 12, fl[200 + 20 + f]);
                    v[d] = dot24h(xh, wl + (40 + f) * 12, fl[200 + 40 + f]);
                }
                // stage K (8B) and V (pair-interleaved u16) — same-wave lockstep
                {
                    uint2 kk;
                    kk.x = h2bits(k[0], k[1]);
                    kk.y = h2bits(k[2], k[3]);
                    *(uint2*)myK = kk;
#pragma unroll
                    for (int d = 0; d < 4; ++d) {
                        _Float16 vh = (_Float16)v[d];
                        myV[d * 2 + vlane] = *reinterpret_cast<const ushort*>(&vh);
                    }
                }
                h2 q01 = bch2(h2bits(q[0], q[1]));
                h2 q23 = bch2(h2bits(q[2], q[3]));
                float den = 0.f, o0 = 0.f, o1 = 0.f, o2 = 0.f, o3 = 0.f;
#pragma unroll 4
                for (int t = 0; t < BB / 2; ++t) {
                    uint2 ka = *(const uint2*)(hwbase + (2 * t) * 12);
                    uint2 kb = *(const uint2*)(hwbase + (2 * t + 1) * 12);
                    uint4 vp = *(const uint4*)(hwbase + (2 * t) * 12 + 4);
                    float s0 = FDOT2(q01, bch2(ka.x), FDOT2(q23, bch2(ka.y), 0.f));
                    float s1 = FDOT2(q01, bch2(kb.x), FDOT2(q23, bch2(kb.y), 0.f));
                    h2 pp = __builtin_bit_cast(h2, __builtin_amdgcn_cvt_pkrtz(exp2f(s0), exp2f(s1)));
                    den = FDOT2(pp, ones, den);
                    o0 = FDOT2(pp, bch2(vp.x), o0);
                    o1 = FDOT2(pp, bch2(vp.y), o1);
                    o2 = FDOT2(pp, bch2(vp.z), o2);
                    o3 = FDOT2(pp, bch2(vp.w), o3);
                }
                float inv = 1.0f / den;
                out[4*h+0] = o0 * inv;
                out[4*h+1] = o1 * inv;
                out[4*h+2] = o2 * inv;
                out[4*h+3] = o3 * inv;
            }
            // out-proj + residual + LN1 (f16 dot2)
            h2 oh[12];
            pack12(oh, out);
            float cr[20];
#pragma unroll
            for (int e = 0; e < 20; ++e)
                cr[e] = x[e] + dot24h(oh, wl + (60 + e) * 12, fl[260 + e]);
            ln_vec<20>(cr, fl + 310, fl + 330);
            // FFN1 (f16 dot2) + FFN2 (f32) + residual + LN2
            h2 ch[12];
            pack12(ch, cr);
            float hb[FFND];
#pragma unroll
            for (int j = 0; j < FFND; ++j)
                hb[j] = fmaxf(dot24h(ch, wl + (80 + j) * 12, fl[280 + j]), 0.f);
#pragma unroll
            for (int e = 0; e < 20; ++e) {
                float acc = fl[290 + e];
#pragma unroll
                for (int m = 0; m < FFND; ++m) acc = fmaf(hb[m], fl[e * FFND + m], acc);
                x[e] = cr[e] + acc;
            }
            ln_vec<20>(x, fl + 350, fl + 370);
        }

        // lin partials for this column into pool (f32, per-lane slot [0..9])
        const float* lwb = linW + (size_t)i * SVS * (SEQL * EMB);
        float* slot = &pool[(hw * BB + s) * 12];
#pragma unroll
        for (int o = 0; o < SVS; ++o) {
            const float* wr = lwb + o * (SEQL * EMB) + col * EMB;
            float acc = 0.f;
#pragma unroll
            for (int j = 0; j < 20; ++j) acc = fmaf(x[j], wr[j], acc);
            slot[o] = acc;
        }
    }
    __syncthreads();

    // block-reduce the (≤8) active columns -> part[i][blk][b][o]  (strided: 320 > 256)
    for (int idx = tid; idx < BB * SVS; idx += NTA) {
        const int b = idx / SVS, o = idx % SVS;
        const int ncols = (blk == 3) ? 1 : 8;
        float acc = 0.f;
        for (int c = 0; c < ncols; ++c) acc += pool[(c * BB + b) * 12 + o];
        part[(((size_t)i * BPI + blk) * BB + b) * SVS + o] = acc;
    }
}

// ---------------- kernel B: lin-bias + st-encoder ----------------
__global__ void __launch_bounds__(NTB)
stenc_kernel(const float* __restrict__ part, const float* __restrict__ linb,
             const float* __restrict__ sWqkv,const float* __restrict__ sbqkv,
             const float* __restrict__ sWo,  const float* __restrict__ sbo,
             const float* __restrict__ sW1,  const float* __restrict__ sb1,
             const float* __restrict__ sW2,  const float* __restrict__ sb2,
             const float* __restrict__ sg1,  const float* __restrict__ sbe1,
             const float* __restrict__ sg2,  const float* __restrict__ sbe2,
             float* __restrict__ sec)
{
    __shared__ float stx[BB][SVS];
    __shared__ float stqkv[BB][3*SVS];
    __shared__ float sttmp[BB][SVS];
    __shared__ float pqW[300], pqB[30], poW[100], poB[10];
    __shared__ float p1W[100], p1B[10], p2W[100], p2B[10];
    __shared__ float pg1[10], pbe1[10], pg2[10], pbe2[10];

    const int i   = blockIdx.x;
    const int tid = threadIdx.x;

    if (tid < BB * SVS) {
        const int b = tid / SVS, o = tid % SVS;
        float acc = linb[i * SVS + o];
#pragma unroll
        for (int blk = 0; blk < BPI; ++blk)
            acc += part[(((size_t)i * BPI + blk) * BB + b) * SVS + o];
        stx[b][o] = acc;
    }

#pragma unroll 1
    for (int l = 0; l < NL; ++l) {
        __syncthreads();
        cp_lds(pqW, sWqkv + l * 300, 300, tid, NTB);
        cp_lds(pqB, sbqkv + l * 30,  30,  tid, NTB);
        cp_lds(poW, sWo   + l * 100, 100, tid, NTB);
        cp_lds(poB, sbo   + l * 10,  10,  tid, NTB);
        cp_lds(p1W, sW1   + l * 100, 100, tid, NTB);
        cp_lds(p1B, sb1   + l * 10,  10,  tid, NTB);
        cp_lds(p2W, sW2   + l * 100, 100, tid, NTB);
        cp_lds(p2B, sb2   + l * 10,  10,  tid, NTB);
        cp_lds(pg1, sg1   + l * 10,  10,  tid, NTB);
        cp_lds(pbe1, sbe1 + l * 10,  10,  tid, NTB);
        cp_lds(pg2, sg2   + l * 10,  10,  tid, NTB);
        cp_lds(pbe2, sbe2 + l * 10,  10,  tid, NTB);
        __syncthreads();

        for (int idx = tid; idx < BB * 3 * SVS; idx += NTB) {   // 960 dots, len 10
            int s2 = idx / (3 * SVS), f = idx % (3 * SVS);
            float acc = pqB[f];
#pragma unroll
            for (int e = 0; e < SVS; e++) acc = fmaf(stx[s2][e], pqW[f * SVS + e], acc);
            stqkv[s2][f] = acc;
        }
        __syncthreads();

        if (tid < BB * NH) {       // attention per (s, h), D=2; single pass
            int s2 = tid / NH, h = tid % NH;
            float q0 = stqkv[s2][h * 2], q1 = stqkv[s2][h * 2 + 1];
            float den = 0.f, o0 = 0.f, o1 = 0.f;
#pragma unroll
            for (int t = 0; t < BB; t++) {
                float d0 = q0 * stqkv[t][SVS + h * 2] + q1 * stqkv[t][SVS + h * 2 + 1];
                float p = __expf(0.70710678118f * d0);
                den += p;
                o0 = fmaf(p, stqkv[t][2 * SVS + h * 2],     o0);
                o1 = fmaf(p, stqkv[t][2 * SVS + h * 2 + 1], o1);
            }
            float inv = 1.0f / den;
            sttmp[s2][h * 2]     = o0 * inv;
            sttmp[s2][h * 2 + 1] = o1 * inv;
        }
        __syncthreads();

        if (tid < BB) {            // proj + LN1 + FFN + LN2, token-local
            int s2 = tid;
            float cr[SVS];
#pragma unroll
            for (int e = 0; e < SVS; e++) {
                float acc = poB[e];
#pragma unroll
                for (int f = 0; f < SVS; f++) acc = fmaf(sttmp[s2][f], poW[e * SVS + f], acc);
                cr[e] = stx[s2][e] + acc;
            }
            ln_vec<SVS>(cr, pg1, pbe1);
            float hb[FFND];
#pragma unroll
            for (int j = 0; j < FFND; j++) {
                float acc = p1B[j];
#pragma unroll
                for (int e = 0; e < SVS; e++) acc = fmaf(cr[e], p1W[j * SVS + e], acc);
                hb[j] = fmaxf(acc, 0.f);
            }
            float fr[SVS];
#pragma unroll
            for (int e = 0; e < SVS; e++) {
                float acc = p2B[e];
#pragma unroll
                for (int j = 0; j < FFND; j++) acc = fmaf(hb[j], p2W[e * FFND + j], acc);
                fr[e] = cr[e] + acc;
            }
            ln_vec<SVS>(fr, pg2, pbe2);
#pragma unroll
            for (int e = 0; e < SVS; e++) stx[s2][e] = fr[e];
        }
        __syncthreads();
    }

    if (tid < BB * SVS) {
        int b = tid / SVS, o = tid % SVS;
        sec[(size_t)b * (NSEQ * SVS) + (size_t)i * SVS + o] = stx[b][o];
    }
}

__global__ __launch_bounds__(256, 1)
void head_kernel(const float* __restrict__ sec,
                 const float* __restrict__ plW, const float* __restrict__ plb,
                 const float* __restrict__ llW, const float* __restrict__ llb,
                 float* __restrict__ out)
{
    const int b = blockIdx.x, tid = threadIdx.x;
    const float* fb = sec + (size_t)b * (NSEQ * SVS);
    float acc[8];
#pragma unroll
    for (int p = 0; p < 8; p++) acc[p] = 0.f;
    for (int f = tid; f < NSEQ * SVS; f += 256) {
        float xv = fb[f];
#pragma unroll
        for (int p = 0; p < 8; p++)
            acc[p] = fmaf(xv, plW[p * (NSEQ * SVS) + f], acc[p]);
    }
#pragma unroll
    for (int p = 0; p < 8; p++) {
#pragma unroll
        for (int off = 32; off > 0; off >>= 1)
            acc[p] += __shfl_down(acc[p], off, 64);
    }
    __shared__ float red[4][8];
    const int wv = tid >> 6, ln = tid & 63;
    if (ln == 0) {
#pragma unroll
        for (int p = 0; p < 8; p++) red[wv][p] = acc[p];
    }
    __syncthreads();
    if (tid == 0) {
        float s8[8];
#pragma unroll
        for (int p = 0; p < 8; p++)
            s8[p] = red[0][p] + red[1][p] + red[2][p] + red[3][p] + plb[p];
#pragma unroll
        for (int qq = 0; qq < 2; qq++) {
            float o = llb[qq];
#pragma unroll
            for (int p = 0; p < 8; p++) o = fmaf(s8[p], llW[qq * 8 + p], o);
            out[b * 2 + qq] = o;
        }
    }
}

extern "C" void kernel_launch(void* const* d_in, const int* in_sizes, int n_in,
                              void* d_out, int out_size, void* d_ws, size_t ws_size,
                              hipStream_t stream)
{
    const float* X     = (const float*)d_in[0];
    const float* Wqkv  = (const float*)d_in[1];
    const float* bqkv  = (const float*)d_in[2];
    const float* Wo    = (const float*)d_in[3];
    const float* bo    = (const float*)d_in[4];
    const float* W1    = (const float*)d_in[5];
    const float* b1    = (const float*)d_in[6];
    const float* W2    = (const float*)d_in[7];
    const float* b2    = (const float*)d_in[8];
    const float* g1    = (const float*)d_in[9];
    const float* be1   = (const float*)d_in[10];
    const float* g2    = (const float*)d_in[11];
    const float* be2   = (const float*)d_in[12];
    const float* linW  = (const float*)d_in[13];
    const float* linb  = (const float*)d_in[14];
    const float* sWqkv = (const float*)d_in[15];
    const float* sbqkv = (const float*)d_in[16];
    const float* sWo   = (const float*)d_in[17];
    const float* sbo   = (const float*)d_in[18];
    const float* sW1   = (const float*)d_in[19];
    const float* sb1   = (const float*)d_in[20];
    const float* sW2   = (const float*)d_in[21];
    const float* sb2   = (const float*)d_in[22];
    const float* sg1   = (const float*)d_in[23];
    const float* sbe1  = (const float*)d_in[24];
    const float* sg2   = (const float*)d_in[25];
    const float* sbe2  = (const float*)d_in[26];
    const float* plW   = (const float*)d_in[27];
    const float* plb   = (const float*)d_in[28];
    const float* llW   = (const float*)d_in[29];
    const float* llb   = (const float*)d_in[30];

    float* part = (float*)d_ws;                         // 430*4*32*10 fp32 = 2,201,600 B
    float* sec  = part + (size_t)NSEQ * BPI * BB * SVS; // 550,400 B more

    ptenc_kernel<<<NSEQ * BPI, NTA, 0, stream>>>(X, Wqkv, bqkv, Wo, bo, W1, b1, W2, b2,
                                                 g1, be1, g2, be2, linW, part);
    stenc_kernel<<<NSEQ, NTB, 0, stream>>>(part, linb,
                                           sWqkv, sbqkv, sWo, sbo, sW1, sb1, sW2, sb2,
                                           sg1, sbe1, sg2, sbe2, sec);
    head_kernel<<<BB, 256, 0, stream>>>(sec, plW, plb, llW, llb, (float*)d_out);
}